// Round 13
// baseline (924.506 us; speedup 1.0000x reference)
//
#include <hip/hip_runtime.h>

// Problem: BiLSTM-CRF tagger NLL (forward only).
// B=64, L=128, E=300, H=256 (per dir), 4H=1024, T=64, V=50000.
//
// ws layout (float units):
//   XP_OFF   = 0           : xp[2][8192][1024] f32
//   LSTM_OFF = 16777216    : lstm_out[8192][512]
//   EM_OFF   = 20971520    : emissions[8192][64]  (doubles as B-frag image
//                            + bias2 during xp_gemm — dead until emis_gemm)
//   WBF_OFF  = 21495808    : w_hh fp8, wave-coalesced uint4 layout (512 KB)
//   NLL_OFF  = 21757952    : per-batch nll [64]
//
// Lessons: R2-5 spills loop-invariant VGPR arrays unless budget allows
// (keep LDS>80KB -> 1 blk/CU -> 128-reg budget, R9). R6 coalesce weights.
// R7-10: DS instruction COUNT on the CU-shared LDS pipe is the wall.
// R11: global_load offset is 13-bit SIGNED -> re-centered bases.
// R12 NaN root cause: vmcnt counts interleaved xp/weight loads wrongly ->
// sc2/sc3 read unlanded weight regs -> fp8 0xFF decodes to NaN. Fix: issue
// all 8 weight loads FIRST (counts 10/8/6/4 exact), xp loads after, uniform
// vmcnt(0) drain before barrier, "=&v" early-clobber on ALL asm load outs.

#define XP_OFF   0
#define LSTM_OFF 16777216
#define EM_OFF   20971520
#define WBF_OFF  21495808
#define NLL_OFF  21757952
#define BIMG_OFF EM_OFF              // 327,680 floats (B fragment image)
#define BIAS_OFF (EM_OFF + 500000)   // 2048 floats (b_ih + b_hh per col)

typedef float v2f __attribute__((ext_vector_type(2)));
typedef unsigned v4u __attribute__((ext_vector_type(4)));
typedef short bf16x8 __attribute__((ext_vector_type(8)));
typedef float f32x4 __attribute__((ext_vector_type(4)));

__device__ __forceinline__ float sigmf(float x) { return 1.f / (1.f + __expf(-x)); }
__device__ __forceinline__ float tanhfast(float x) {
    float t = __expf(2.f * x);
    return 1.f - 2.f / (t + 1.f);
}
__device__ __forceinline__ unsigned short f2bf(float f) {
    unsigned u = __float_as_uint(f);
    return (unsigned short)((u + 0x7fffu + ((u >> 16) & 1u)) >> 16);
}
__device__ __forceinline__ unsigned packbf(float a, float b) {
    return (unsigned)f2bf(a) | ((unsigned)f2bf(b) << 16);
}

// ---- fp8 e4m3fn encode (RNE), |x| <= 4.0 guaranteed by caller ----
__device__ __forceinline__ unsigned enc8(float x) {
    unsigned s = (__float_as_uint(x) >> 31) << 7;
    float a = fabsf(x);
    if (a >= 0.015625f) {
        int e; float m = frexpf(a, &e);
        float q = rintf(m * 16.f);
        if (q >= 16.f) { q = 8.f; e += 1; }
        int E = e - 1 + 7;
        return s | (unsigned)(E << 3) | (unsigned)((int)q - 8);
    } else {
        float q = rintf(a * 512.f);
        if (q >= 8.f) return s | (1u << 3);
        return s | (unsigned)(int)q;
    }
}
__device__ __forceinline__ v2f dec2lo(unsigned v) {
    return __builtin_amdgcn_cvt_pk_f32_fp8((int)v, false);
}
__device__ __forceinline__ v2f dec2hi(unsigned v) {
    return __builtin_amdgcn_cvt_pk_f32_fp8((int)v, true);
}

// ---------------- K0: repack w_hh (f32 -> fp8 e4m3, scaled x64) -------------
// uint4 index = half*16384 + ((dir*16 + w)*8 + q)*64 + ln  (half0 = i,f
// register-cached; half1 = g,o streamed).  Thread t=w*64+ln, r=t&255, kq=t>>8.
//   half0: gate = q>>2 (0=i,1=f), q4 = q&3
//   half1: gate = 2+(q&1) (2=g,3=o), q4 = q>>1
//   dword i covers k = kq*64 + q4*16 + i*4 .. +3 of row gate*256+r.
__global__ __launch_bounds__(256) void cvt_whh_fp8(
    const float* __restrict__ wf, const float* __restrict__ wb,
    unsigned int* __restrict__ out)
{
    int idx = blockIdx.x * 256 + threadIdx.x;
    int i    = idx & 3;
    int ln   = (idx >> 2) & 63;
    int q    = (idx >> 8) & 7;
    int w    = (idx >> 11) & 15;
    int dir  = (idx >> 15) & 1;
    int half = (idx >> 16) & 1;
    const float* wsrc = dir ? wb : wf;
    int t = w * 64 + ln;
    int r = t & 255, kq = t >> 8;
    int g_, q4;
    if (half == 0) { g_ = q >> 2;       q4 = q & 3;  }
    else           { g_ = 2 + (q & 1);  q4 = q >> 1; }
    int row = g_ * 256 + r;
    int k0 = kq * 64 + q4 * 16 + i * 4;
    const float* src = wsrc + (size_t)row * 256 + k0;
    unsigned o = 0;
    #pragma unroll
    for (int j = 0; j < 4; ++j) o |= enc8(src[j] * 64.f) << (8 * j);
    out[idx] = o;
}

// ---------------- K0b: prep B fragment image + bias2 ----------------
// B[k][n] = w_ih_dir[n&1023][k] as bf16, fragment-linear:
// lane = ((k&31)>>3)<<4 | (n&15); elem j = k&7; block = (n>>4)*10 + (k>>5).
__global__ __launch_bounds__(64) void prep_b(
    const float* __restrict__ wf, const float* __restrict__ wb,
    const float* __restrict__ bif, const float* __restrict__ bhf,
    const float* __restrict__ bib, const float* __restrict__ bhb,
    unsigned* __restrict__ bimg, float* __restrict__ bias2)
{
    int n = blockIdx.x;               // 0..2047
    int dir = n >> 10, nr = n & 1023;
    int k8 = threadIdx.x;
    if (k8 < 40) {
        const float* wsrc = dir ? wb : wf;
        float v[8];
        #pragma unroll
        for (int j = 0; j < 8; ++j) {
            int k = k8 * 8 + j;
            v[j] = (k < 300) ? wsrc[(size_t)nr * 300 + k] : 0.f;
        }
        int ntg = n >> 4, kt = k8 >> 2;
        int lane = ((k8 & 3) << 4) | (n & 15);
        unsigned* dst = bimg + (((size_t)(ntg * 10 + kt)) * 64 + lane) * 4;
        dst[0] = packbf(v[0], v[1]); dst[1] = packbf(v[2], v[3]);
        dst[2] = packbf(v[4], v[5]); dst[3] = packbf(v[6], v[7]);
    } else if (k8 == 40) {
        bias2[n] = (dir ? bib : bif)[nr] + (dir ? bhb : bhf)[nr];
    }
}

// ---------------- K1: xp GEMM via bf16 MFMA ----------------
// xp[m][n] = emb[sent[m]] . w_ih[n] + bias2[n].  M=8192, N=2048, K=300(->320).
// BM=128, BN=128, grid(64,16), 256 thr / 4 waves (2x2), wave = 64x64,
// 4x4 mfma_f32_16x16x32_bf16 tiles, acc init = bias.
__global__ __launch_bounds__(256) void xp_gemm(
    const int* __restrict__ sent, const float* __restrict__ emb,
    const unsigned* __restrict__ bimg, const float* __restrict__ bias2,
    float* __restrict__ xp)
{
    __shared__ __align__(16) unsigned short Alds[128 * 328]; // bf16, stride 656B
    __shared__ int sidx[128];
    const int tid = threadIdx.x;
    const int m0 = blockIdx.x * 128;
    const int by = blockIdx.y;
    if (tid < 128) sidx[tid] = sent[m0 + tid];
    __syncthreads();
    // zero-pad k = 300..319
    #pragma unroll
    for (int i2 = 0; i2 < 5; ++i2) {
        int f2 = i2 * 256 + tid;                 // < 1280
        int row = (f2 * 6554) >> 16;             // /10
        int d = f2 - row * 10;
        *(unsigned*)((char*)Alds + row * 656 + 600 + d * 4) = 0;
    }
    // gather emb rows + convert to bf16: 128 rows x 75 float4
    for (int it = 0; it < 38; ++it) {
        int f = it * 256 + tid;
        if (f < 9600) {
            int row = (int)(((unsigned)f * 55925u) >> 22);   // /75
            int c4 = f - row * 75;
            float4 v = *(const float4*)&emb[(size_t)sidx[row] * 300 + c4 * 4];
            uint2 p; p.x = packbf(v.x, v.y); p.y = packbf(v.z, v.w);
            *(uint2*)((char*)Alds + row * 656 + c4 * 8) = p;
        }
    }
    __syncthreads();
    const int l = tid & 63, wid = tid >> 6;
    const int wy = wid >> 1, wx = wid & 1;
    const int lhi = l >> 4, llo = l & 15;
    f32x4 acc[4][4];
    #pragma unroll
    for (int nt = 0; nt < 4; ++nt) {
        float bv = bias2[by * 128 + wx * 64 + nt * 16 + llo];
        #pragma unroll
        for (int mt = 0; mt < 4; ++mt) acc[mt][nt] = (f32x4){bv, bv, bv, bv};
    }
    const char* abase = (const char*)Alds + (size_t)(wy * 64 + llo) * 656 + lhi * 16;
    const unsigned* bb = bimg + (((size_t)((by * 8 + wx * 4) * 10)) * 64 + l) * 4;
    for (int kt = 0; kt < 10; ++kt) {
        bf16x8 a[4], b[4];
        #pragma unroll
        for (int mt = 0; mt < 4; ++mt)
            a[mt] = *(const bf16x8*)(abase + mt * 16 * 656 + kt * 64);
        #pragma unroll
        for (int nt = 0; nt < 4; ++nt)
            b[nt] = *(const bf16x8*)(bb + (nt * 10 + kt) * 256);
        #pragma unroll
        for (int mt = 0; mt < 4; ++mt)
            #pragma unroll
            for (int nt = 0; nt < 4; ++nt)
                acc[mt][nt] = __builtin_amdgcn_mfma_f32_16x16x32_bf16(
                    a[mt], b[nt], acc[mt][nt], 0, 0, 0);
    }
    const int dir = by >> 3;
    const int n0 = (by & 7) * 128 + wx * 64;
    float* outp = xp + (size_t)dir * 8388608;
    #pragma unroll
    for (int mt = 0; mt < 4; ++mt) {
        int row = m0 + wy * 64 + mt * 16 + lhi * 4;
        #pragma unroll
        for (int nt = 0; nt < 4; ++nt) {
            int col = n0 + nt * 16 + llo;
            #pragma unroll
            for (int j = 0; j < 4; ++j)
                outp[(size_t)(row + j) * 1024 + col] = acc[mt][nt][j];
        }
    }
}

// ---------------- K2: LSTM recurrence ----------------
// 128 blocks = (dir, batch), dir = (bid&7)>>2.  1024 threads.
// Thread t: r=t&255 (unit), kq=t>>8. Owns all 4 gates of unit r over
// k in [kq*64, kq*64+64).  i,f weights in 8 asm-pinned registers.
// g,o streamed under exact counted vmcnt; h bf16 in LDS (8 uniform b128).
__global__ __launch_bounds__(1024) void lstm_rec(
    const float* __restrict__ xp, const unsigned int* __restrict__ w8,
    float* __restrict__ lstm_out)
{
    const int bid = blockIdx.x;
    const int r8  = bid & 7;
    const int dir = r8 >> 2;
    const int b   = ((bid >> 3) << 2) | (r8 & 3);
    const int t  = threadIdx.x;
    const int w  = t >> 6;
    const int ln = t & 63;
    const int r  = t & 255;
    const int kq = t >> 8;
    __shared__ __align__(16) unsigned short hs[256];   // h bf16
    __shared__ __align__(16) float part2[4][256][4];   // [kq][unit][gate]
    __shared__ v4u lds_pad[4352];     // 68KB pad -> total ~85KB -> 1 blk/CU
    if (bid > 100000) ((volatile float*)lds_pad)[t] = 0.f;  // keep pad live

    const v4u* w4 = (const v4u*)w8;
    // re-centered bases: 13-bit signed offsets span -4096..+3072 (R11 fix)
    const v4u* cbase = w4 + ((size_t)(dir * 16 + w) * 8 + 4) * 64 + ln;
    const v4u* sbase = w4 + 16384 + ((size_t)(dir * 16 + w) * 8 + 4) * 64 + ln;
    const unsigned hofs = (unsigned)(size_t)&hs[0] + (unsigned)kq * 128;

    // pin cached i,f weight quads in registers (asm: cannot be sunk/remat'd)
    v4u ci0, ci1, ci2, ci3, cf0, cf1, cf2, cf3;
    asm volatile(
        "global_load_dwordx4 %0, %8, off offset:-4096\n\t"
        "global_load_dwordx4 %1, %8, off offset:-3072\n\t"
        "global_load_dwordx4 %2, %8, off offset:-2048\n\t"
        "global_load_dwordx4 %3, %8, off offset:-1024\n\t"
        "global_load_dwordx4 %4, %8, off\n\t"
        "global_load_dwordx4 %5, %8, off offset:1024\n\t"
        "global_load_dwordx4 %6, %8, off offset:2048\n\t"
        "global_load_dwordx4 %7, %8, off offset:3072\n\t"
        "s_waitcnt vmcnt(0)"
        : "=&v"(ci0), "=&v"(ci1), "=&v"(ci2), "=&v"(ci3),
          "=&v"(cf0), "=&v"(cf1), "=&v"(cf2), "=&v"(cf3)
        : "v"(cbase));

    float c = 0.f;
    if (t < 256) hs[t] = 0;
    const float* xpb = xp + (size_t)dir * 8388608 + (size_t)b * 131072;
    const int dl = dir ? -1 : 1;
    int l = dir ? 127 : 0;
    float* lob = lstm_out + (size_t)b * 65536 + dir * 256 + r;
    __syncthreads();

#define LDG(reg, off) asm volatile("global_load_dwordx4 %0, %1, off offset:" off \
                                   : "=&v"(reg) : "v"(sbase))
#define DSRH(reg, off) asm volatile("ds_read_b128 %0, %1 offset:" off \
                                    : "=&v"(reg) : "v"(hofs))
#define WAITL(N) { asm volatile("s_waitcnt lgkmcnt(" #N ")" ::: "memory"); \
                   __builtin_amdgcn_sched_barrier(0); }
#define WAITV(N) { asm volatile("s_waitcnt vmcnt(" #N ")" ::: "memory"); \
                   __builtin_amdgcn_sched_barrier(0); }
#define UNPK(p, d) { p.x = __uint_as_float((unsigned)(d) << 16); \
                     p.y = __uint_as_float((unsigned)(d) & 0xffff0000u); }
#define MAC1(wi, wf_, wg, wo, d) \
    ai += dec2lo(wi[d]) * pa;  ai += dec2hi(wi[d]) * pb; \
    af += dec2lo(wf_[d]) * pa; af += dec2hi(wf_[d]) * pb; \
    ag += dec2lo(wg[d]) * pa;  ag += dec2hi(wg[d]) * pb; \
    ao += dec2lo(wo[d]) * pa;  ao += dec2hi(wo[d]) * pb;
#define FMAC(hx, hy, wi, wf_, wg, wo) { v2f pa, pb; \
    UNPK(pa, hx[0]) UNPK(pb, hx[1]) MAC1(wi, wf_, wg, wo, 0) \
    UNPK(pa, hx[2]) UNPK(pb, hx[3]) MAC1(wi, wf_, wg, wo, 1) \
    UNPK(pa, hy[0]) UNPK(pb, hy[1]) MAC1(wi, wf_, wg, wo, 2) \
    UNPK(pa, hy[2]) UNPK(pb, hy[3]) MAC1(wi, wf_, wg, wo, 3) }

    for (int s = 0; s < 128; ++s) {
        // ---- issue ALL 8 streamed g/o loads first (vmcnt-oldest), then xp ----
        v4u sg0, so0, sg1, so1, sg2, so2, sg3, so3;
        LDG(sg0, "-4096"); LDG(so0, "-3072"); LDG(sg1, "-2048"); LDG(so1, "-1024");
        LDG(sg2, "0");     LDG(so2, "1024");  LDG(sg3, "2048");  LDG(so3, "3072");
        float x0, x1, x2, x3;
        {
            const float* xcur = xpb + (size_t)l * 1024 + r;
            asm volatile("global_load_dword %0, %4, off\n\t"
                         "global_load_dword %1, %4, off offset:1024\n\t"
                         "global_load_dword %2, %4, off offset:2048\n\t"
                         "global_load_dword %3, %4, off offset:3072"
                         : "=&v"(x0), "=&v"(x1), "=&v"(x2), "=&v"(x3) : "v"(xcur));
        }
        // VMEM queue (oldest->newest): sg0,so0,sg1,so1,sg2,so2,sg3,so3,x0..x3
        v4u hA0, hA1, hB0, hB1;
        DSRH(hA0, "0"); DSRH(hA1, "16"); DSRH(hB0, "32"); DSRH(hB1, "48");
        v2f ai = {0.f, 0.f}, af = {0.f, 0.f}, ag = {0.f, 0.f}, ao = {0.f, 0.f};
        // sc0: need sg0,so0 -> 12 outstanding, complete 2 oldest
        WAITL(2); WAITV(10);
        FMAC(hA0, hA1, ci0, cf0, sg0, so0)
        DSRH(hA0, "64"); DSRH(hA1, "80");
        // sc1: need sg1,so1
        WAITL(2); WAITV(8);
        FMAC(hB0, hB1, ci1, cf1, sg1, so1)
        DSRH(hB0, "96"); DSRH(hB1, "112");
        // sc2: need sg2,so2
        WAITL(2); WAITV(6);
        FMAC(hA0, hA1, ci2, cf2, sg2, so2)
        // sc3: need sg3,so3 (x0..x3 remain outstanding)
        WAITL(0); WAITV(4);
        FMAC(hB0, hB1, ci3, cf3, sg3, so3)

        *(float4*)&part2[kq][r][0] =
            make_float4(ai.x + ai.y, af.x + af.y, ag.x + ag.y, ao.x + ao.y);
        WAITV(0);          // drain xp loads in ALL threads (uniform queue/step)
        __syncthreads();
        if (t < 256) {
            float4 q0 = *(const float4*)&part2[0][t][0];
            float4 q1 = *(const float4*)&part2[1][t][0];
            float4 q2 = *(const float4*)&part2[2][t][0];
            float4 q3 = *(const float4*)&part2[3][t][0];
            float gi = fmaf(q0.x + q1.x + q2.x + q3.x, 0.015625f, x0);
            float gf = fmaf(q0.y + q1.y + q2.y + q3.y, 0.015625f, x1);
            float gg = fmaf(q0.z + q1.z + q2.z + q3.z, 0.015625f, x2);
            float go = fmaf(q0.w + q1.w + q2.w + q3.w, 0.015625f, x3);
            c = sigmf(gf) * c + sigmf(gi) * tanhfast(gg);
            float h = sigmf(go) * tanhfast(c);
            hs[t] = f2bf(h);
            lob[(size_t)l * 512] = h;
        }
        __syncthreads();
        l += dl;
    }
#undef LDG
#undef DSRH
#undef WAITL
#undef WAITV
#undef UNPK
#undef MAC1
#undef FMAC
}

// ---------------- K3: emissions GEMM ----------------
__global__ __launch_bounds__(256) void emis_gemm(
    const float* __restrict__ lo, const float* __restrict__ w_out,
    const float* __restrict__ b_out, float* __restrict__ em)
{
    __shared__ float as[64][64];
    __shared__ float bs[64][64];
    const int tid = threadIdx.x;
    const int m0 = blockIdx.x * 64;
    const int mr = tid & 63;
    const int kq = tid >> 6;
    const int rb = (tid & 15) * 4;
    const int cb = (tid >> 4) * 4;
    float acc[4][4] = {};
    for (int kc = 0; kc < 8; ++kc) {
        const int k0 = kc * 64;
        #pragma unroll
        for (int i = 0; i < 4; ++i) {
            const int k = kq * 16 + 4 * i;
            float4 va = *(const float4*)&lo[(size_t)(m0 + mr) * 512 + k0 + k];
            as[k][mr] = va.x; as[k + 1][mr] = va.y; as[k + 2][mr] = va.z; as[k + 3][mr] = va.w;
            float4 vb = *(const float4*)&w_out[(size_t)mr * 512 + k0 + k];
            bs[k][mr] = vb.x; bs[k + 1][mr] = vb.y; bs[k + 2][mr] = vb.z; bs[k + 3][mr] = vb.w;
        }
        __syncthreads();
        #pragma unroll 8
        for (int kk = 0; kk < 64; ++kk) {
            float a[4], bb[4];
            *(float4*)a  = *(const float4*)&as[kk][rb];
            *(float4*)bb = *(const float4*)&bs[kk][cb];
            #pragma unroll
            for (int i = 0; i < 4; ++i)
                #pragma unroll
                for (int jj = 0; jj < 4; ++jj)
                    acc[i][jj] += a[i] * bb[jj];
        }
        __syncthreads();
    }
    float4 bo = *(const float4*)&b_out[cb];
    #pragma unroll
    for (int i = 0; i < 4; ++i) {
        float4 o = make_float4(acc[i][0] + bo.x, acc[i][1] + bo.y,
                               acc[i][2] + bo.z, acc[i][3] + bo.w);
        *(float4*)&em[(size_t)(m0 + rb + i) * 64 + cb] = o;
    }
}

// ---------------- K4: CRF numerator + forward algorithm ----------------
__global__ __launch_bounds__(256) void crf_kernel(
    const float* __restrict__ em, const int* __restrict__ tags,
    const float* __restrict__ start_t, const float* __restrict__ end_t,
    const float* __restrict__ trans, float* __restrict__ nll)
{
    const int b = blockIdx.x;
    const int tid = threadIdx.x;
    const int j = tid & 63;
    const int q = tid >> 6;
    __shared__ float s_lds[64];
    __shared__ float part[4][64];
    __shared__ float m_sh, num_sh;
    float tr[16];
    #pragma unroll
    for (int ii = 0; ii < 16; ++ii) tr[ii] = trans[(q * 16 + ii) * 64 + j];
    const float* emb_b = em + (size_t)b * 8192;
    const int* tg_b = tags + b * 128;
    float numpart = 0.f;
    if (tid < 128) {
        int l = tid;
        int tg = tg_b[l];
        numpart = emb_b[l * 64 + tg];
        if (l < 127) numpart += trans[tg * 64 + tg_b[l + 1]];
        if (l == 0)  numpart += start_t[tg];
        if (l == 127) numpart += end_t[tg];
    }
    float red = numpart;
    #pragma unroll
    for (int off = 32; off >= 1; off >>= 1) red += __shfl_xor(red, off);
    if (j == 0) part[q][0] = red;
    if (q == 0) s_lds[j] = start_t[j] + emb_b[j];
    __syncthreads();
    if (tid == 0) num_sh = part[0][0] + part[1][0] + part[2][0] + part[3][0];
    __syncthreads();
    for (int l = 1; l < 128; ++l) {
        if (q == 0) {
            float v = s_lds[j];
            #pragma unroll
            for (int off = 32; off >= 1; off >>= 1) v = fmaxf(v, __shfl_xor(v, off));
            if (j == 0) m_sh = v;
        }
        __syncthreads();
        const float m = m_sh;
        float sv[16];
        #pragma unroll
        for (int t4 = 0; t4 < 4; ++t4) {
            float4 v = *(const float4*)&s_lds[q * 16 + 4 * t4];
            sv[4 * t4] = v.x; sv[4 * t4 + 1] = v.y; sv[4 * t4 + 2] = v.z; sv[4 * t4 + 3] = v.w;
        }
        float acc = 0.f;
        #pragma unroll
        for (int ii = 0; ii < 16; ++ii) acc += __expf(sv[ii] + tr[ii] - m);
        part[q][j] = acc;
        __syncthreads();
        if (q == 0) {
            float t = part[0][j] + part[1][j] + part[2][j] + part[3][j];
            s_lds[j] = m + __logf(t) + emb_b[l * 64 + j];
        }
    }
    if (q == 0) {
        float v = s_lds[j] + end_t[j];
        float mm = v;
        #pragma unroll
        for (int off = 32; off >= 1; off >>= 1) mm = fmaxf(mm, __shfl_xor(mm, off));
        float e = __expf(v - mm);
        #pragma unroll
        for (int off = 32; off >= 1; off >>= 1) e += __shfl_xor(e, off);
        if (j == 0) nll[b] = (mm + __logf(e)) - num_sh;
    }
}

// ---------------- K5: final mean ----------------
__global__ void finalize(const float* __restrict__ nll, float* __restrict__ out)
{
    int j = threadIdx.x;
    float v = nll[j];
    #pragma unroll
    for (int off = 32; off >= 1; off >>= 1) v += __shfl_xor(v, off);
    if (j == 0) out[0] = v * (1.f / 64.f);
}

extern "C" void kernel_launch(void* const* d_in, const int* in_sizes, int n_in,
                              void* d_out, int out_size, void* d_ws, size_t ws_size,
                              hipStream_t stream) {
    const int* sent      = (const int*)d_in[0];
    const int* tags      = (const int*)d_in[1];
    const float* emb     = (const float*)d_in[2];
    const float* w_ih_f  = (const float*)d_in[3];
    const float* w_hh_f  = (const float*)d_in[4];
    const float* b_ih_f  = (const float*)d_in[5];
    const float* b_hh_f  = (const float*)d_in[6];
    const float* w_ih_b  = (const float*)d_in[7];
    const float* w_hh_b  = (const float*)d_in[8];
    const float* b_ih_b  = (const float*)d_in[9];
    const float* b_hh_b  = (const float*)d_in[10];
    const float* w_out   = (const float*)d_in[11];
    const float* b_out   = (const float*)d_in[12];
    const float* start_t = (const float*)d_in[13];
    const float* end_t   = (const float*)d_in[14];
    const float* trans   = (const float*)d_in[15];

    float* ws = (float*)d_ws;
    float* xp        = ws + XP_OFF;
    float* lstm_out  = ws + LSTM_OFF;
    float* em        = ws + EM_OFF;
    unsigned int* w8 = (unsigned int*)(ws + WBF_OFF);
    float* nll       = ws + NLL_OFF;
    unsigned* bimg   = (unsigned*)(ws + BIMG_OFF);
    float* bias2     = ws + BIAS_OFF;

    cvt_whh_fp8<<<dim3(512), dim3(256), 0, stream>>>(w_hh_f, w_hh_b, w8);
    prep_b<<<dim3(2048), dim3(64), 0, stream>>>(w_ih_f, w_ih_b,
        b_ih_f, b_hh_f, b_ih_b, b_hh_b, bimg, bias2);
    xp_gemm<<<dim3(64, 16), dim3(256), 0, stream>>>(sent, emb, bimg, bias2, xp);
    lstm_rec<<<dim3(128), dim3(1024), 0, stream>>>(xp, w8, lstm_out);
    emis_gemm<<<dim3(128), dim3(256), 0, stream>>>(lstm_out, w_out, b_out, em);
    crf_kernel<<<dim3(64), dim3(256), 0, stream>>>(em, tags, start_t, end_t, trans, nll);
    finalize<<<dim3(1), dim3(64), 0, stream>>>(nll, (float*)d_out);
}

// Round 14
// 626.739 us; speedup vs baseline: 1.4751x; 1.4751x over previous
//
#include <hip/hip_runtime.h>

// Problem: BiLSTM-CRF tagger NLL (forward only).
// B=64, L=128, E=300, H=256 (per dir), 4H=1024, T=64, V=50000.
//
// ws layout (float units):
//   XP_OFF   = 0           : xp[2][8192][1024] f32
//   LSTM_OFF = 16777216    : lstm_out[8192][512]
//   EM_OFF   = 20971520    : emissions[8192][64]  (doubles as B-frag image
//                            + bias2 during xp_gemm — dead until emis_gemm)
//   WBF_OFF  = 21495808    : w_hh fp8, wave-coalesced uint4 layout (512 KB)
//   NLL_OFF  = 21757952    : per-batch nll [64]
//
// Allocator law (R2-R13): 1024-thread workgroups are hard-capped at 64 VGPRs
// (R4/5/9/13 all spilled at demand>64); 512-thread workgroups get 128
// (R2/R3 measured). R14: back to 512 threads/block — thread owns all 4
// gates of unit r over k-half kh (8 subchunks). i,f weights LDS-cached
// (128 KB); g,o streamed from L2 under exact counted vmcnt; h bf16 in LDS;
// DS pipelined 1 subchunk ahead (lgkmcnt(4)). Live regs ~95 < 128.

#define XP_OFF   0
#define LSTM_OFF 16777216
#define EM_OFF   20971520
#define WBF_OFF  21495808
#define NLL_OFF  21757952
#define BIMG_OFF EM_OFF              // 327,680 floats (B fragment image)
#define BIAS_OFF (EM_OFF + 500000)   // 2048 floats (b_ih + b_hh per col)

typedef float v2f __attribute__((ext_vector_type(2)));
typedef unsigned v4u __attribute__((ext_vector_type(4)));
typedef short bf16x8 __attribute__((ext_vector_type(8)));
typedef float f32x4 __attribute__((ext_vector_type(4)));

__device__ __forceinline__ float sigmf(float x) { return 1.f / (1.f + __expf(-x)); }
__device__ __forceinline__ float tanhfast(float x) {
    float t = __expf(2.f * x);
    return 1.f - 2.f / (t + 1.f);
}
__device__ __forceinline__ unsigned short f2bf(float f) {
    unsigned u = __float_as_uint(f);
    return (unsigned short)((u + 0x7fffu + ((u >> 16) & 1u)) >> 16);
}
__device__ __forceinline__ unsigned packbf(float a, float b) {
    return (unsigned)f2bf(a) | ((unsigned)f2bf(b) << 16);
}

// ---- fp8 e4m3fn encode (RNE), |x| <= 4.0 guaranteed by caller ----
__device__ __forceinline__ unsigned enc8(float x) {
    unsigned s = (__float_as_uint(x) >> 31) << 7;
    float a = fabsf(x);
    if (a >= 0.015625f) {
        int e; float m = frexpf(a, &e);
        float q = rintf(m * 16.f);
        if (q >= 16.f) { q = 8.f; e += 1; }
        int E = e - 1 + 7;
        return s | (unsigned)(E << 3) | (unsigned)((int)q - 8);
    } else {
        float q = rintf(a * 512.f);
        if (q >= 8.f) return s | (1u << 3);
        return s | (unsigned)(int)q;
    }
}
__device__ __forceinline__ v2f dec2lo(unsigned v) {
    return __builtin_amdgcn_cvt_pk_f32_fp8((int)v, false);
}
__device__ __forceinline__ v2f dec2hi(unsigned v) {
    return __builtin_amdgcn_cvt_pk_f32_fp8((int)v, true);
}

// ---------------- K0: repack w_hh (f32 -> fp8 e4m3, scaled x64) -------------
// Quad index = half*16384 + ((dir*8 + w)*16 + q)*64 + ln.
// Thread t = w*64+ln: r = t&255, kh = t>>8 (= w>>2).
//   half0 (i,f; LDS-cached): gate = q>>3, sc = q&7
//   half1 (g,o; streamed)  : gate = 2+(q&1), sc = q>>1
//   dword i covers k = kh*128 + sc*16 + i*4 .. +3 of row gate*256+r.
__global__ __launch_bounds__(256) void cvt_whh_fp8(
    const float* __restrict__ wf, const float* __restrict__ wb,
    unsigned int* __restrict__ out)
{
    int idx = blockIdx.x * 256 + threadIdx.x;   // dword 0..131071
    int i    = idx & 3;
    int ln   = (idx >> 2) & 63;
    int q    = (idx >> 8) & 15;
    int w    = (idx >> 12) & 7;
    int dir  = (idx >> 15) & 1;
    int half = (idx >> 16) & 1;
    const float* wsrc = dir ? wb : wf;
    int t = w * 64 + ln;
    int r = t & 255, kh = t >> 8;
    int g_, sc;
    if (half == 0) { g_ = q >> 3;       sc = q & 7;  }
    else           { g_ = 2 + (q & 1);  sc = q >> 1; }
    int row = g_ * 256 + r;
    int k0 = kh * 128 + sc * 16 + i * 4;
    const float* src = wsrc + (size_t)row * 256 + k0;
    unsigned o = 0;
    #pragma unroll
    for (int j = 0; j < 4; ++j) o |= enc8(src[j] * 64.f) << (8 * j);
    out[idx] = o;
}

// ---------------- K0b: prep B fragment image + bias2 ----------------
__global__ __launch_bounds__(64) void prep_b(
    const float* __restrict__ wf, const float* __restrict__ wb,
    const float* __restrict__ bif, const float* __restrict__ bhf,
    const float* __restrict__ bib, const float* __restrict__ bhb,
    unsigned* __restrict__ bimg, float* __restrict__ bias2)
{
    int n = blockIdx.x;               // 0..2047
    int dir = n >> 10, nr = n & 1023;
    int k8 = threadIdx.x;
    if (k8 < 40) {
        const float* wsrc = dir ? wb : wf;
        float v[8];
        #pragma unroll
        for (int j = 0; j < 8; ++j) {
            int k = k8 * 8 + j;
            v[j] = (k < 300) ? wsrc[(size_t)nr * 300 + k] : 0.f;
        }
        int ntg = n >> 4, kt = k8 >> 2;
        int lane = ((k8 & 3) << 4) | (n & 15);
        unsigned* dst = bimg + (((size_t)(ntg * 10 + kt)) * 64 + lane) * 4;
        dst[0] = packbf(v[0], v[1]); dst[1] = packbf(v[2], v[3]);
        dst[2] = packbf(v[4], v[5]); dst[3] = packbf(v[6], v[7]);
    } else if (k8 == 40) {
        bias2[n] = (dir ? bib : bif)[nr] + (dir ? bhb : bhf)[nr];
    }
}

// ---------------- K1: xp GEMM via bf16 MFMA ----------------
__global__ __launch_bounds__(256) void xp_gemm(
    const int* __restrict__ sent, const float* __restrict__ emb,
    const unsigned* __restrict__ bimg, const float* __restrict__ bias2,
    float* __restrict__ xp)
{
    __shared__ __align__(16) unsigned short Alds[128 * 328]; // bf16, stride 656B
    __shared__ int sidx[128];
    const int tid = threadIdx.x;
    const int m0 = blockIdx.x * 128;
    const int by = blockIdx.y;
    if (tid < 128) sidx[tid] = sent[m0 + tid];
    __syncthreads();
    #pragma unroll
    for (int i2 = 0; i2 < 5; ++i2) {
        int f2 = i2 * 256 + tid;
        int row = (f2 * 6554) >> 16;             // /10
        int d = f2 - row * 10;
        *(unsigned*)((char*)Alds + row * 656 + 600 + d * 4) = 0;
    }
    for (int it = 0; it < 38; ++it) {
        int f = it * 256 + tid;
        if (f < 9600) {
            int row = (int)(((unsigned)f * 55925u) >> 22);   // /75
            int c4 = f - row * 75;
            float4 v = *(const float4*)&emb[(size_t)sidx[row] * 300 + c4 * 4];
            uint2 p; p.x = packbf(v.x, v.y); p.y = packbf(v.z, v.w);
            *(uint2*)((char*)Alds + row * 656 + c4 * 8) = p;
        }
    }
    __syncthreads();
    const int l = tid & 63, wid = tid >> 6;
    const int wy = wid >> 1, wx = wid & 1;
    const int lhi = l >> 4, llo = l & 15;
    f32x4 acc[4][4];
    #pragma unroll
    for (int nt = 0; nt < 4; ++nt) {
        float bv = bias2[by * 128 + wx * 64 + nt * 16 + llo];
        #pragma unroll
        for (int mt = 0; mt < 4; ++mt) acc[mt][nt] = (f32x4){bv, bv, bv, bv};
    }
    const char* abase = (const char*)Alds + (size_t)(wy * 64 + llo) * 656 + lhi * 16;
    const unsigned* bb = bimg + (((size_t)((by * 8 + wx * 4) * 10)) * 64 + l) * 4;
    for (int kt = 0; kt < 10; ++kt) {
        bf16x8 a[4], b[4];
        #pragma unroll
        for (int mt = 0; mt < 4; ++mt)
            a[mt] = *(const bf16x8*)(abase + mt * 16 * 656 + kt * 64);
        #pragma unroll
        for (int nt = 0; nt < 4; ++nt)
            b[nt] = *(const bf16x8*)(bb + (nt * 10 + kt) * 256);
        #pragma unroll
        for (int mt = 0; mt < 4; ++mt)
            #pragma unroll
            for (int nt = 0; nt < 4; ++nt)
                acc[mt][nt] = __builtin_amdgcn_mfma_f32_16x16x32_bf16(
                    a[mt], b[nt], acc[mt][nt], 0, 0, 0);
    }
    const int dir = by >> 3;
    const int n0 = (by & 7) * 128 + wx * 64;
    float* outp = xp + (size_t)dir * 8388608;
    #pragma unroll
    for (int mt = 0; mt < 4; ++mt) {
        int row = m0 + wy * 64 + mt * 16 + lhi * 4;
        #pragma unroll
        for (int nt = 0; nt < 4; ++nt) {
            int col = n0 + nt * 16 + llo;
            #pragma unroll
            for (int j = 0; j < 4; ++j)
                outp[(size_t)(row + j) * 1024 + col] = acc[mt][nt][j];
        }
    }
}

// ---------------- K2: LSTM recurrence, 512 threads ----------------
// 128 blocks = (dir, batch), dir = (bid&7)>>2.  512 threads.
// Thread t: r = t&255 (unit), kh = t>>8 (k-half). Owns all 4 gates of unit r
// over k in [kh*128, kh*128+128) = 8 subchunks of 16.
// i,f weights LDS-cached (128 KB, read 2 b128/sc); g,o streamed from L2
// (2 dwordx4/sc, exact counted vmcnt); h bf16 in LDS (2 b128/sc).
__global__ __launch_bounds__(512) void lstm_rec(
    const float* __restrict__ xp, const unsigned int* __restrict__ w8,
    float* __restrict__ lstm_out)
{
    const int bid = blockIdx.x;
    const int r8  = bid & 7;
    const int dir = r8 >> 2;
    const int b   = ((bid >> 3) << 2) | (r8 & 3);
    const int t  = threadIdx.x;
    const int w  = t >> 6;      // 0..7
    const int ln = t & 63;
    const int r  = t & 255;
    const int kh = t >> 8;      // 0..1
    __shared__ __align__(16) unsigned short hs[256];   // h bf16
    __shared__ __align__(16) float part2[2][256][4];   // [kh][unit][gate]
    __shared__ v4u wl[8192];                           // 128 KB cached i,f

    const v4u* w4 = (const v4u*)w8;
    #pragma unroll
    for (int q = 0; q < 16; ++q)
        wl[(w * 16 + q) * 64 + ln] = w4[((size_t)(dir * 8 + w) * 16 + q) * 64 + ln];

    // streamed bases (13-bit signed offsets): A covers q0..7, B covers q8..15
    const v4u* sbA = w4 + 16384 + ((size_t)(dir * 8 + w) * 16 + 4)  * 64 + ln;
    const v4u* sbB = w4 + 16384 + ((size_t)(dir * 8 + w) * 16 + 12) * 64 + ln;
    const unsigned wofs = (unsigned)(size_t)&wl[0] + (unsigned)(w * 16384 + ln * 16);
    const unsigned hofs = (unsigned)(size_t)&hs[0] + (unsigned)(kh * 256);

    float c = 0.f;
    if (t < 256) hs[t] = 0;
    const float* xpb = xp + (size_t)dir * 8388608 + (size_t)b * 131072;
    const int dl = dir ? -1 : 1;
    int l = dir ? 127 : 0;
    float* lob = lstm_out + (size_t)b * 65536 + dir * 256 + r;
    __syncthreads();

#define LDGA(reg, off) asm volatile("global_load_dwordx4 %0, %1, off offset:" off \
                                    : "=&v"(reg) : "v"(sbA))
#define LDGB(reg, off) asm volatile("global_load_dwordx4 %0, %1, off offset:" off \
                                    : "=&v"(reg) : "v"(sbB))
#define DSH(reg, off) asm volatile("ds_read_b128 %0, %1 offset:" off \
                                   : "=&v"(reg) : "v"(hofs))
#define DSW(reg, off) asm volatile("ds_read_b128 %0, %1 offset:" off \
                                   : "=&v"(reg) : "v"(wofs))
#define WAITL(N) { asm volatile("s_waitcnt lgkmcnt(" #N ")" ::: "memory"); \
                   __builtin_amdgcn_sched_barrier(0); }
#define WAITV(N) { asm volatile("s_waitcnt vmcnt(" #N ")" ::: "memory"); \
                   __builtin_amdgcn_sched_barrier(0); }
#define UNPK(p, d) { p.x = __uint_as_float((unsigned)(d) << 16); \
                     p.y = __uint_as_float((unsigned)(d) & 0xffff0000u); }
#define MAC1(wi, wf_, wg, wo, d) \
    ai += dec2lo(wi[d]) * pa;  ai += dec2hi(wi[d]) * pb; \
    af += dec2lo(wf_[d]) * pa; af += dec2hi(wf_[d]) * pb; \
    ag += dec2lo(wg[d]) * pa;  ag += dec2hi(wg[d]) * pb; \
    ao += dec2lo(wo[d]) * pa;  ao += dec2hi(wo[d]) * pb;
#define FMAC(hx, hy, wi, wf_, wg, wo) { v2f pa, pb; \
    UNPK(pa, hx[0]) UNPK(pb, hx[1]) MAC1(wi, wf_, wg, wo, 0) \
    UNPK(pa, hx[2]) UNPK(pb, hx[3]) MAC1(wi, wf_, wg, wo, 1) \
    UNPK(pa, hy[0]) UNPK(pb, hy[1]) MAC1(wi, wf_, wg, wo, 2) \
    UNPK(pa, hy[2]) UNPK(pb, hy[3]) MAC1(wi, wf_, wg, wo, 3) }

    for (int s = 0; s < 128; ++s) {
        // ---- streamed g,o for sc0..3 (8 quads, vmcnt-oldest), then xp ----
        v4u g0, o0, g1, o1, g2, o2, g3, o3;
        LDGA(g0, "-4096"); LDGA(o0, "-3072"); LDGA(g1, "-2048"); LDGA(o1, "-1024");
        LDGA(g2, "0");     LDGA(o2, "1024");  LDGA(g3, "2048");  LDGA(o3, "3072");
        float x0, x1, x2, x3;                      // all threads (uniform queue)
        {
            const float* xcur = xpb + (size_t)l * 1024 + r;
            asm volatile("global_load_dword %0, %4, off\n\t"
                         "global_load_dword %1, %4, off offset:1024\n\t"
                         "global_load_dword %2, %4, off offset:2048\n\t"
                         "global_load_dword %3, %4, off offset:3072"
                         : "=&v"(x0), "=&v"(x1), "=&v"(x2), "=&v"(x3) : "v"(xcur));
        }
        // VMEM queue: g0,o0,g1,o1,g2,o2,g3,o3, x0..x3, [in-loop: 8 more]
        v4u hA0, hA1, wiA, wfA, hB0, hB1, wiB, wfB;
        DSH(hA0, "0"); DSH(hA1, "16"); DSW(wiA, "0"); DSW(wfA, "8192");
        v2f ai = {0.f, 0.f}, af = {0.f, 0.f}, ag = {0.f, 0.f}, ao = {0.f, 0.f};
        // sc0
        DSH(hB0, "32"); DSH(hB1, "48"); DSW(wiB, "1024"); DSW(wfB, "9216");
        WAITL(4); WAITV(10);
        FMAC(hA0, hA1, wiA, wfA, g0, o0)
        LDGB(g0, "-4096"); LDGB(o0, "-3072");      // sc4 quads
        // sc1
        DSH(hA0, "64"); DSH(hA1, "80"); DSW(wiA, "2048"); DSW(wfA, "10240");
        WAITL(4); WAITV(10);
        FMAC(hB0, hB1, wiB, wfB, g1, o1)
        LDGB(g1, "-2048"); LDGB(o1, "-1024");      // sc5
        // sc2
        DSH(hB0, "96"); DSH(hB1, "112"); DSW(wiB, "3072"); DSW(wfB, "11264");
        WAITL(4); WAITV(10);
        FMAC(hA0, hA1, wiA, wfA, g2, o2)
        LDGB(g2, "0"); LDGB(o2, "1024");           // sc6
        // sc3
        DSH(hA0, "128"); DSH(hA1, "144"); DSW(wiA, "4096"); DSW(wfA, "12288");
        WAITL(4); WAITV(10);
        FMAC(hB0, hB1, wiB, wfB, g3, o3)
        LDGB(g3, "2048"); LDGB(o3, "3072");        // sc7
        // sc4
        DSH(hB0, "160"); DSH(hB1, "176"); DSW(wiB, "5120"); DSW(wfB, "13312");
        WAITL(4); WAITV(6);                        // drains x0..x3 + g0,o0
        FMAC(hA0, hA1, wiA, wfA, g0, o0)
        // sc5
        DSH(hA0, "192"); DSH(hA1, "208"); DSW(wiA, "6144"); DSW(wfA, "14336");
        WAITL(4); WAITV(4);
        FMAC(hB0, hB1, wiB, wfB, g1, o1)
        // sc6
        DSH(hB0, "224"); DSH(hB1, "240"); DSW(wiB, "7168"); DSW(wfB, "15360");
        WAITL(4); WAITV(2);
        FMAC(hA0, hA1, wiA, wfA, g2, o2)
        // sc7
        WAITL(0); WAITV(0);
        FMAC(hB0, hB1, wiB, wfB, g3, o3)

        *(float4*)&part2[kh][r][0] =
            make_float4(ai.x + ai.y, af.x + af.y, ag.x + ag.y, ao.x + ao.y);
        __syncthreads();
        if (t < 256) {
            float4 q0 = *(const float4*)&part2[0][t][0];
            float4 q1 = *(const float4*)&part2[1][t][0];
            float gi = fmaf(q0.x + q1.x, 0.015625f, x0);
            float gf = fmaf(q0.y + q1.y, 0.015625f, x1);
            float gg = fmaf(q0.z + q1.z, 0.015625f, x2);
            float go = fmaf(q0.w + q1.w, 0.015625f, x3);
            c = sigmf(gf) * c + sigmf(gi) * tanhfast(gg);
            float h = sigmf(go) * tanhfast(c);
            hs[t] = f2bf(h);
            lob[(size_t)l * 512] = h;
        }
        __syncthreads();
        l += dl;
    }
#undef LDGA
#undef LDGB
#undef DSH
#undef DSW
#undef WAITL
#undef WAITV
#undef UNPK
#undef MAC1
#undef FMAC
}

// ---------------- K3: emissions GEMM ----------------
__global__ __launch_bounds__(256) void emis_gemm(
    const float* __restrict__ lo, const float* __restrict__ w_out,
    const float* __restrict__ b_out, float* __restrict__ em)
{
    __shared__ float as[64][64];
    __shared__ float bs[64][64];
    const int tid = threadIdx.x;
    const int m0 = blockIdx.x * 64;
    const int mr = tid & 63;
    const int kq = tid >> 6;
    const int rb = (tid & 15) * 4;
    const int cb = (tid >> 4) * 4;
    float acc[4][4] = {};
    for (int kc = 0; kc < 8; ++kc) {
        const int k0 = kc * 64;
        #pragma unroll
        for (int i = 0; i < 4; ++i) {
            const int k = kq * 16 + 4 * i;
            float4 va = *(const float4*)&lo[(size_t)(m0 + mr) * 512 + k0 + k];
            as[k][mr] = va.x; as[k + 1][mr] = va.y; as[k + 2][mr] = va.z; as[k + 3][mr] = va.w;
            float4 vb = *(const float4*)&w_out[(size_t)mr * 512 + k0 + k];
            bs[k][mr] = vb.x; bs[k + 1][mr] = vb.y; bs[k + 2][mr] = vb.z; bs[k + 3][mr] = vb.w;
        }
        __syncthreads();
        #pragma unroll 8
        for (int kk = 0; kk < 64; ++kk) {
            float a[4], bb[4];
            *(float4*)a  = *(const float4*)&as[kk][rb];
            *(float4*)bb = *(const float4*)&bs[kk][cb];
            #pragma unroll
            for (int i = 0; i < 4; ++i)
                #pragma unroll
                for (int jj = 0; jj < 4; ++jj)
                    acc[i][jj] += a[i] * bb[jj];
        }
        __syncthreads();
    }
    float4 bo = *(const float4*)&b_out[cb];
    #pragma unroll
    for (int i = 0; i < 4; ++i) {
        float4 o = make_float4(acc[i][0] + bo.x, acc[i][1] + bo.y,
                               acc[i][2] + bo.z, acc[i][3] + bo.w);
        *(float4*)&em[(size_t)(m0 + rb + i) * 64 + cb] = o;
    }
}

// ---------------- K4: CRF numerator + forward algorithm ----------------
__global__ __launch_bounds__(256) void crf_kernel(
    const float* __restrict__ em, const int* __restrict__ tags,
    const float* __restrict__ start_t, const float* __restrict__ end_t,
    const float* __restrict__ trans, float* __restrict__ nll)
{
    const int b = blockIdx.x;
    const int tid = threadIdx.x;
    const int j = tid & 63;
    const int q = tid >> 6;
    __shared__ float s_lds[64];
    __shared__ float part[4][64];
    __shared__ float m_sh, num_sh;
    float tr[16];
    #pragma unroll
    for (int ii = 0; ii < 16; ++ii) tr[ii] = trans[(q * 16 + ii) * 64 + j];
    const float* emb_b = em + (size_t)b * 8192;
    const int* tg_b = tags + b * 128;
    float numpart = 0.f;
    if (tid < 128) {
        int l = tid;
        int tg = tg_b[l];
        numpart = emb_b[l * 64 + tg];
        if (l < 127) numpart += trans[tg * 64 + tg_b[l + 1]];
        if (l == 0)  numpart += start_t[tg];
        if (l == 127) numpart += end_t[tg];
    }
    float red = numpart;
    #pragma unroll
    for (int off = 32; off >= 1; off >>= 1) red += __shfl_xor(red, off);
    if (j == 0) part[q][0] = red;
    if (q == 0) s_lds[j] = start_t[j] + emb_b[j];
    __syncthreads();
    if (tid == 0) num_sh = part[0][0] + part[1][0] + part[2][0] + part[3][0];
    __syncthreads();
    for (int l = 1; l < 128; ++l) {
        if (q == 0) {
            float v = s_lds[j];
            #pragma unroll
            for (int off = 32; off >= 1; off >>= 1) v = fmaxf(v, __shfl_xor(v, off));
            if (j == 0) m_sh = v;
        }
        __syncthreads();
        const float m = m_sh;
        float sv[16];
        #pragma unroll
        for (int t4 = 0; t4 < 4; ++t4) {
            float4 v = *(const float4*)&s_lds[q * 16 + 4 * t4];
            sv[4 * t4] = v.x; sv[4 * t4 + 1] = v.y; sv[4 * t4 + 2] = v.z; sv[4 * t4 + 3] = v.w;
        }
        float acc = 0.f;
        #pragma unroll
        for (int ii = 0; ii < 16; ++ii) acc += __expf(sv[ii] + tr[ii] - m);
        part[q][j] = acc;
        __syncthreads();
        if (q == 0) {
            float t = part[0][j] + part[1][j] + part[2][j] + part[3][j];
            s_lds[j] = m + __logf(t) + emb_b[l * 64 + j];
        }
    }
    if (q == 0) {
        float v = s_lds[j] + end_t[j];
        float mm = v;
        #pragma unroll
        for (int off = 32; off >= 1; off >>= 1) mm = fmaxf(mm, __shfl_xor(mm, off));
        float e = __expf(v - mm);
        #pragma unroll
        for (int off = 32; off >= 1; off >>= 1) e += __shfl_xor(e, off);
        if (j == 0) nll[b] = (mm + __logf(e)) - num_sh;
    }
}

// ---------------- K5: final mean ----------------
__global__ void finalize(const float* __restrict__ nll, float* __restrict__ out)
{
    int j = threadIdx.x;
    float v = nll[j];
    #pragma unroll
    for (int off = 32; off >= 1; off >>= 1) v += __shfl_xor(v, off);
    if (j == 0) out[0] = v * (1.f / 64.f);
}

extern "C" void kernel_launch(void* const* d_in, const int* in_sizes, int n_in,
                              void* d_out, int out_size, void* d_ws, size_t ws_size,
                              hipStream_t stream) {
    const int* sent      = (const int*)d_in[0];
    const int* tags      = (const int*)d_in[1];
    const float* emb     = (const float*)d_in[2];
    const float* w_ih_f  = (const float*)d_in[3];
    const float* w_hh_f  = (const float*)d_in[4];
    const float* b_ih_f  = (const float*)d_in[5];
    const float* b_hh_f  = (const float*)d_in[6];
    const float* w_ih_b  = (const float*)d_in[7];
    const float* w_hh_b  = (const float*)d_in[8];
    const float* b_ih_b  = (const float*)d_in[9];
    const float* b_hh_b  = (const float*)d_in[10];
    const float* w_out   = (const float*)d_in[11];
    const float* b_out   = (const float*)d_in[12];
    const float* start_t = (const float*)d_in[13];
    const float* end_t   = (const float*)d_in[14];
    const float* trans   = (const float*)d_in[15];

    float* ws = (float*)d_ws;
    float* xp        = ws + XP_OFF;
    float* lstm_out  = ws + LSTM_OFF;
    float* em        = ws + EM_OFF;
    unsigned int* w8 = (unsigned int*)(ws + WBF_OFF);
    float* nll       = ws + NLL_OFF;
    unsigned* bimg   = (unsigned*)(ws + BIMG_OFF);
    float* bias2     = ws + BIAS_OFF;

    cvt_whh_fp8<<<dim3(512), dim3(256), 0, stream>>>(w_hh_f, w_hh_b, w8);
    prep_b<<<dim3(2048), dim3(64), 0, stream>>>(w_ih_f, w_ih_b,
        b_ih_f, b_hh_f, b_ih_b, b_hh_b, bimg, bias2);
    xp_gemm<<<dim3(64, 16), dim3(256), 0, stream>>>(sent, emb, bimg, bias2, xp);
    lstm_rec<<<dim3(128), dim3(512), 0, stream>>>(xp, w8, lstm_out);
    emis_gemm<<<dim3(128), dim3(256), 0, stream>>>(lstm_out, w_out, b_out, em);
    crf_kernel<<<dim3(64), dim3(256), 0, stream>>>(em, tags, start_t, end_t, trans, nll);
    finalize<<<dim3(1), dim3(64), 0, stream>>>(nll, (float*)d_out);
}